// Round 1
// baseline (354.261 us; speedup 1.0000x reference)
//
#include <hip/hip_runtime.h>
#include <math.h>

#define Bn 4
#define Nn 2048
#define Hn 8
#define HDn 32
#define Dn 256
#define MHALF 1024  // m-split: 2 partials merged in oproj
#define NT 16       // q-rows per attn block (was 32): 2x blocks -> 4 blocks/CU

typedef _Float16 h1;
typedef __attribute__((ext_vector_type(8))) _Float16 h8;
typedef __attribute__((ext_vector_type(4))) float fx4;

#define QSCALE 0.35355339059327373f
// |S_raw| <= HD = 32, |S_raw*QSCALE*topo| <= 11.32 -> fixed softmax shift safe:
// p = e^{S-4} in [2.2e-7, 1503] -- fits f16, no running max needed.
#define SOFTMAX_SHIFT 4.0f

// ---------------------------------------------------------------------------
// Kernel 0: W -> f16 transpose via LDS tiles (coalesced both sides)
// ---------------------------------------------------------------------------
__global__ __launch_bounds__(256) void cvtW_kernel(
    const float* __restrict__ Wq, const float* __restrict__ Wk,
    const float* __restrict__ Wv, h1* __restrict__ WT)
{
    __shared__ float tw[64][65];
    const int w = blockIdx.z;
    const int d0 = blockIdx.y * 64, o0 = blockIdx.x * 64;
    const float* W = (w == 0) ? Wq : (w == 1) ? Wk : Wv;
    const int rr = threadIdx.x >> 6, cc = threadIdx.x & 63;
#pragma unroll
    for (int i = 0; i < 16; ++i)
        tw[rr + i * 4][cc] = W[(size_t)(d0 + rr + i * 4) * 256 + o0 + cc];
    __syncthreads();
#pragma unroll
    for (int i = 0; i < 16; ++i) {
        const int row = rr + i * 4;
        WT[(size_t)w * 65536 + (size_t)(o0 + row) * 256 + d0 + cc] = (h1)tw[cc][row];
    }
}

// ---------------------------------------------------------------------------
// Kernel 1: QKV projection via f16 MFMA (x split hi/lo for ~f32 accuracy).
// ---------------------------------------------------------------------------
__global__ __launch_bounds__(256) __attribute__((amdgpu_waves_per_eu(4, 4)))
void proj_kernel(
    const float* __restrict__ x, const h1* __restrict__ WT,
    const float* __restrict__ bq, const float* __restrict__ bk,
    const float* __restrict__ bv,
    h1* __restrict__ fq, h1* __restrict__ fk, h1* __restrict__ vT)
{
    __shared__ __align__(16) h1 fbuf[64][264];
    const int tid = threadIdx.x;
    const int w = tid >> 6;
    const int lane = tid & 63;
    const int quad = lane >> 4;
    const int l15 = lane & 15;
    const int wsel = blockIdx.y >> 1;
    const int hg = blockIdx.y & 1;
    const int r0 = blockIdx.x * 64;
    const int arow = r0 + w * 16 + l15;
    const int b = r0 >> 11, n0 = r0 & (Nn - 1);

    const h1* WTw = WT + (size_t)wsel * 65536;
    fx4 acc[8];
#pragma unroll
    for (int ct = 0; ct < 8; ++ct) acc[ct] = (fx4){0.f, 0.f, 0.f, 0.f};

    for (int ks = 0; ks < 8; ++ks) {
        float xv[8];
        *(float4*)&xv[0] = *(const float4*)&x[(size_t)arow * 256 + ks * 32 + quad * 8];
        *(float4*)&xv[4] = *(const float4*)&x[(size_t)arow * 256 + ks * 32 + quad * 8 + 4];
        h8 Ahi, Alo;
#pragma unroll
        for (int j = 0; j < 8; ++j) {
            const h1 hi = (h1)xv[j];
            Ahi[j] = hi;
            Alo[j] = (h1)(xv[j] - (float)hi);
        }
        h8 Bf[8];
#pragma unroll
        for (int ct = 0; ct < 8; ++ct)
            Bf[ct] = *(const h8*)&WTw[(size_t)(hg * 128 + ct * 16 + l15) * 256 + ks * 32 + quad * 8];
#pragma unroll
        for (int ct = 0; ct < 8; ++ct) {
            acc[ct] = __builtin_amdgcn_mfma_f32_16x16x32_f16(Ahi, Bf[ct], acc[ct], 0, 0, 0);
            acc[ct] = __builtin_amdgcn_mfma_f32_16x16x32_f16(Alo, Bf[ct], acc[ct], 0, 0, 0);
        }
    }

    const float* bias = (wsel == 0) ? bq : (wsel == 1) ? bk : bv;

    if (wsel < 2) {
        h1* f = (wsel == 0) ? fq : fk;
#pragma unroll
        for (int ct = 0; ct < 8; ++ct) {
            const int c = ct * 16 + l15;
            const float bb = bias[hg * 128 + c];
            const int hh4 = c >> 5, dd = c & 31;
#pragma unroll
            for (int r = 0; r < 4; ++r) {
                const float val = acc[ct][r] + bb;
                const float sv = __sinf(val), cv = __cosf(val);
                h1* fp = &fbuf[w * 16 + quad * 4 + r][hh4 * 64 + dd];
                fp[0]  = (h1)cv;
                fp[32] = (h1)sv;
            }
        }
        __syncthreads();
        const int row = tid >> 2, q4 = tid & 3;
#pragma unroll
        for (int g = 0; g < 8; ++g) {
            const int chunk = q4 + g * 4;
            const int hh4 = chunk >> 3, within = chunk & 7;
            const h8 val = *(const h8*)&fbuf[row][hh4 * 64 + within * 8];
            const int head = hg * 4 + hh4;
            *(h8*)&f[((size_t)(b * Hn + head) * Nn + n0 + row) * 64 + within * 8] = val;
        }
    } else {
        h1 (*vst)[132] = (h1(*)[132])fbuf;
#pragma unroll
        for (int ct = 0; ct < 8; ++ct) {
            const int c = ct * 16 + l15;
            const float bb = bias[hg * 128 + c];
#pragma unroll
            for (int r = 0; r < 4; ++r)
                vst[w * 16 + quad * 4 + r][c] = (h1)(acc[ct][r] + bb);
        }
        __syncthreads();
        const int c2 = tid & 127, half = tid >> 7;
        const int head = hg * 4 + (c2 >> 5), dd = c2 & 31;
        h1* vp = vT + ((size_t)((b * Hn + head) * HDn + dd)) * Nn + n0;
#pragma unroll
        for (int g = 0; g < 4; ++g) {
            const int gg = half * 4 + g;
            h8 pk;
#pragma unroll
            for (int j = 0; j < 8; ++j) pk[j] = vst[gg * 8 + j][c2];
            *(h8*)(vp + gg * 8) = pk;
        }
    }
}

// ---------------------------------------------------------------------------
// Kernel 2: fused attention. Block = 512 thr = 8 waves = ALL 8 heads of one
// (b, NT=16 q-rows, m-half) -> topo tile shared block-wide (67 MB HBM min).
// CHANGE vs r7: q-tile 32 -> 16 rows. Grid 512 -> 1024 blocks = 4 blocks/CU
// = 32 waves/CU (was 2 blocks/CU, occupancy hard-capped at 50%/measured 41%).
// The kernel is latency-bound (MfmaUtil 9%, VALUBusy 27%, HBM 12%), so 2x
// resident blocks per CU hide the per-iteration chain (L2 K-loads -> MFMA ->
// exp/LDS -> MFMA) across independent blocks. Zero extra HBM traffic: topo
// n-tiles are disjoint, pacc/pl totals unchanged, K/V stay L2-served.
// LDS 29.2 KB -> 14.5 KB/block; VGPR must stay <= 64 for 8 waves/SIMD ->
// __launch_bounds__(512, 8).
// Topo pipelined through an LDS double buffer with a register prefetch and a
// RAW s_barrier (lgkmcnt(0) only) so the global prefetch stays in flight.
// Fixed-shift softmax: no reductions in the loop.
// ---------------------------------------------------------------------------
__global__ __launch_bounds__(512, 8) void attn_kernel(
    const h1* __restrict__ fq, const h1* __restrict__ fk, const h1* __restrict__ vT,
    const float* __restrict__ topo, float* __restrict__ pacc, float* __restrict__ pl)
{
    __shared__ __align__(16) h1 Pw[8][NT][40];   // 10.2 KB per-wave P buffers
    __shared__ float tbuf[2][NT][33];            // 4.2 KB topo double buffer

    const int b = blockIdx.y;
    const int mh = blockIdx.z;
    const int n0 = blockIdx.x * NT;
    const int tid = threadIdx.x;
    const int w = tid >> 6;        // wave id = head
    const int h = w;
    const int lane = tid & 63;
    const int quad = lane >> 4;
    const int l15 = lane & 15;

    const h1* qfh = fq + (size_t)(b * Hn + h) * Nn * 64;
    const h1* kfh = fk + (size_t)(b * Hn + h) * Nn * 64;
    const h1* vTh = vT + (size_t)(b * Hn + h) * HDn * Nn;

    // topo cooperative-load mapping: thread -> (row, col); 16x32 f32 tile
    const int trow = tid >> 5, tcol = tid & 31;
    const float* tpg = topo + (size_t)b * Nn * Nn + (size_t)(n0 + trow) * Nn + tcol;

    h8 qfr[2];
#pragma unroll
    for (int ks = 0; ks < 2; ++ks)
        qfr[ks] = *(const h8*)(qfh + (size_t)(n0 + l15) * 64 + ks * 32 + quad * 8);

    fx4 acc[2];
    float lsum[4];
#pragma unroll
    for (int ds = 0; ds < 2; ++ds) acc[ds] = (fx4){0.f, 0.f, 0.f, 0.f};
#pragma unroll
    for (int r = 0; r < 4; ++r) lsum[r] = 0.f;

    const int mbase = mh * MHALF;
    const fx4 z4 = {0.f, 0.f, 0.f, 0.f};

    float rt = tpg[mbase];   // prefetch tile 0

    for (int it = 0; it < MHALF / 32; ++it) {
        const int m0 = mbase + it * 32;
        const int cur = it & 1;

        // commit prefetched topo tile to LDS, issue next tile's load
        tbuf[cur][trow][tcol] = rt;
        if (it < MHALF / 32 - 1) rt = tpg[m0 + 32];
        // raw barrier: waits own LDS writes only; global prefetch stays in flight
        __asm__ volatile("s_waitcnt lgkmcnt(0)\n\ts_barrier" ::: "memory");

        // K fragments + V fragments (per-head, L2-served)
        h8 kfr[2][2];
#pragma unroll
        for (int ms = 0; ms < 2; ++ms)
#pragma unroll
            for (int ks = 0; ks < 2; ++ks)
                kfr[ms][ks] = *(const h8*)(kfh + (size_t)(m0 + ms * 16 + l15) * 64 + ks * 32 + quad * 8);
        h8 bV[2];
#pragma unroll
        for (int ds = 0; ds < 2; ++ds)
            bV[ds] = *(const h8*)(vTh + (size_t)(ds * 16 + l15) * Nn + m0 + quad * 8);

        // S = Qf @ Kf^T
        fx4 S[2];
#pragma unroll
        for (int ms = 0; ms < 2; ++ms) {
            fx4 tmp = __builtin_amdgcn_mfma_f32_16x16x32_f16(qfr[0], kfr[ms][0], z4, 0, 0, 0);
            S[ms] = __builtin_amdgcn_mfma_f32_16x16x32_f16(qfr[1], kfr[ms][1], tmp, 0, 0, 0);
        }

        // p = e^{S*topo*QSCALE - 4}; topo from LDS
#pragma unroll
        for (int ms = 0; ms < 2; ++ms)
#pragma unroll
            for (int r = 0; r < 4; ++r) {
                const float tv = tbuf[cur][quad * 4 + r][ms * 16 + l15];
                const float p = __expf(fmaf(S[ms][r] * tv, QSCALE, -SOFTMAX_SHIFT));
                lsum[r] += p;
                Pw[w][quad * 4 + r][ms * 16 + l15] = (h1)p;
            }
        __asm__ volatile("s_waitcnt lgkmcnt(0)" ::: "memory");

        // PV
        h8 aP = *(const h8*)&Pw[w][l15][quad * 8];
#pragma unroll
        for (int ds = 0; ds < 2; ++ds)
            acc[ds] = __builtin_amdgcn_mfma_f32_16x16x32_f16(aP, bV[ds], acc[ds], 0, 0, 0);
    }

    // epilogue: reduce l across the 16 col-lanes, write partials
#pragma unroll
    for (int r = 0; r < 4; ++r)
#pragma unroll
        for (int off = 1; off <= 8; off <<= 1)
            lsum[r] += __shfl_xor(lsum[r], off);

    float* paccm = pacc + (size_t)mh * Bn * Nn * Dn;
    float* plm   = pl   + (size_t)mh * Bn * Nn * Hn;
#pragma unroll
    for (int r = 0; r < 4; ++r) {
        const size_t grow = (size_t)b * Nn + n0 + quad * 4 + r;
        paccm[grow * Dn + h * HDn + l15]      = acc[0][r];
        paccm[grow * Dn + h * HDn + 16 + l15] = acc[1][r];
        if (l15 == 0) plm[grow * Hn + h] = lsum[r];
    }
}

// ---------------------------------------------------------------------------
// Kernel 3: merge 2 partials + output projection. 8 rows/block, thread=col.
// ---------------------------------------------------------------------------
__global__ __launch_bounds__(256) void oproj_kernel(
    const float* __restrict__ pacc, const float* __restrict__ pl,
    const float* __restrict__ Wo, const float* __restrict__ bo,
    float* __restrict__ out)
{
    __shared__ float ysT[256][12];
    const int t = threadIdx.x;
    const int r0 = blockIdx.x * 8;
    const int h = t >> 5;
    const size_t PACC = (size_t)Bn * Nn * Dn;
    const size_t PL = (size_t)Bn * Nn * Hn;
#pragma unroll
    for (int i = 0; i < 8; ++i) {
        const size_t row = (size_t)(r0 + i);
        float l = 0.f, yv = 0.f;
#pragma unroll
        for (int m = 0; m < 2; ++m) {
            l  += pl[m * PL + row * Hn + h];
            yv += pacc[m * PACC + row * Dn + t];
        }
        ysT[t][i] = yv * __builtin_amdgcn_rcpf(l);
    }
    __syncthreads();

    float acc8[8];
#pragma unroll
    for (int i = 0; i < 8; ++i) acc8[i] = 0.f;
#pragma unroll 4
    for (int d = 0; d < 256; ++d) {
        const float wv = Wo[d * 256 + t];
        float yy[8];
        *(float4*)&yy[0] = *(const float4*)&ysT[d][0];
        *(float4*)&yy[4] = *(const float4*)&ysT[d][4];
#pragma unroll
        for (int i = 0; i < 8; ++i) acc8[i] = fmaf(yy[i], wv, acc8[i]);
    }
    const float bb = bo[t];
#pragma unroll
    for (int i = 0; i < 8; ++i)
        out[(size_t)(r0 + i) * 256 + t] = acc8[i] + bb;
}

// ---------------------------------------------------------------------------
extern "C" void kernel_launch(void* const* d_in, const int* in_sizes, int n_in,
                              void* d_out, int out_size, void* d_ws, size_t ws_size,
                              hipStream_t stream)
{
    const float* x    = (const float*)d_in[0];
    const float* topo = (const float*)d_in[1];
    const float* Wq   = (const float*)d_in[2];
    const float* bq   = (const float*)d_in[3];
    const float* Wk   = (const float*)d_in[4];
    const float* bk   = (const float*)d_in[5];
    const float* Wv   = (const float*)d_in[6];
    const float* bv   = (const float*)d_in[7];
    const float* Wo   = (const float*)d_in[8];
    const float* bo   = (const float*)d_in[9];
    float* out = (float*)d_out;

    char* ws = (char*)d_ws;
    const size_t MB = 1024 * 1024;
    h1* WT = (h1*)ws;
    h1* fq = (h1*)(ws + 1 * MB);
    h1* fk = (h1*)(ws + 9 * MB);
    h1* vT = (h1*)(ws + 17 * MB);
    float* pacc = (float*)(ws + 21 * MB);
    float* pl   = (float*)(ws + 37 * MB);

    cvtW_kernel<<<dim3(4, 4, 3), 256, 0, stream>>>(Wq, Wk, Wv, WT);
    proj_kernel<<<dim3(128, 6), 256, 0, stream>>>(x, WT, bq, bk, bv, fq, fk, vT);
    attn_kernel<<<dim3(Nn / NT, Bn, 2), 512, 0, stream>>>(fq, fk, vT, topo, pacc, pl);
    oproj_kernel<<<(Bn * Nn) / 8, 256, 0, stream>>>(pacc, pl, Wo, bo, out);
}

// Round 2
// 265.235 us; speedup vs baseline: 1.3357x; 1.3357x over previous
//
#include <hip/hip_runtime.h>
#include <math.h>

#define Bn 4
#define Nn 2048
#define Hn 8
#define HDn 32
#define Dn 256
#define MHALF 1024  // m-split: 2 partials merged in oproj

typedef _Float16 h1;
typedef __attribute__((ext_vector_type(8))) _Float16 h8;
typedef __attribute__((ext_vector_type(4))) float fx4;

#define QSCALE 0.35355339059327373f
// |S_raw| <= HD = 32, |S_raw*QSCALE*topo| <= 11.32 -> fixed softmax shift safe:
// p = e^{S-4} in [2.2e-7, 1503] -- fits f16, no running max needed.
#define SOFTMAX_SHIFT 4.0f

// ---------------------------------------------------------------------------
// Kernel 0: W -> f16 transpose via LDS tiles (coalesced both sides)
// ---------------------------------------------------------------------------
__global__ __launch_bounds__(256) void cvtW_kernel(
    const float* __restrict__ Wq, const float* __restrict__ Wk,
    const float* __restrict__ Wv, h1* __restrict__ WT)
{
    __shared__ float tw[64][65];
    const int w = blockIdx.z;
    const int d0 = blockIdx.y * 64, o0 = blockIdx.x * 64;
    const float* W = (w == 0) ? Wq : (w == 1) ? Wk : Wv;
    const int rr = threadIdx.x >> 6, cc = threadIdx.x & 63;
#pragma unroll
    for (int i = 0; i < 16; ++i)
        tw[rr + i * 4][cc] = W[(size_t)(d0 + rr + i * 4) * 256 + o0 + cc];
    __syncthreads();
#pragma unroll
    for (int i = 0; i < 16; ++i) {
        const int row = rr + i * 4;
        WT[(size_t)w * 65536 + (size_t)(o0 + row) * 256 + d0 + cc] = (h1)tw[cc][row];
    }
}

// ---------------------------------------------------------------------------
// Kernel 1: QKV projection via f16 MFMA (x split hi/lo for ~f32 accuracy).
// ---------------------------------------------------------------------------
__global__ __launch_bounds__(256) __attribute__((amdgpu_waves_per_eu(4, 4)))
void proj_kernel(
    const float* __restrict__ x, const h1* __restrict__ WT,
    const float* __restrict__ bq, const float* __restrict__ bk,
    const float* __restrict__ bv,
    h1* __restrict__ fq, h1* __restrict__ fk, h1* __restrict__ vT)
{
    __shared__ __align__(16) h1 fbuf[64][264];
    const int tid = threadIdx.x;
    const int w = tid >> 6;
    const int lane = tid & 63;
    const int quad = lane >> 4;
    const int l15 = lane & 15;
    const int wsel = blockIdx.y >> 1;
    const int hg = blockIdx.y & 1;
    const int r0 = blockIdx.x * 64;
    const int arow = r0 + w * 16 + l15;
    const int b = r0 >> 11, n0 = r0 & (Nn - 1);

    const h1* WTw = WT + (size_t)wsel * 65536;
    fx4 acc[8];
#pragma unroll
    for (int ct = 0; ct < 8; ++ct) acc[ct] = (fx4){0.f, 0.f, 0.f, 0.f};

    for (int ks = 0; ks < 8; ++ks) {
        float xv[8];
        *(float4*)&xv[0] = *(const float4*)&x[(size_t)arow * 256 + ks * 32 + quad * 8];
        *(float4*)&xv[4] = *(const float4*)&x[(size_t)arow * 256 + ks * 32 + quad * 8 + 4];
        h8 Ahi, Alo;
#pragma unroll
        for (int j = 0; j < 8; ++j) {
            const h1 hi = (h1)xv[j];
            Ahi[j] = hi;
            Alo[j] = (h1)(xv[j] - (float)hi);
        }
        h8 Bf[8];
#pragma unroll
        for (int ct = 0; ct < 8; ++ct)
            Bf[ct] = *(const h8*)&WTw[(size_t)(hg * 128 + ct * 16 + l15) * 256 + ks * 32 + quad * 8];
#pragma unroll
        for (int ct = 0; ct < 8; ++ct) {
            acc[ct] = __builtin_amdgcn_mfma_f32_16x16x32_f16(Ahi, Bf[ct], acc[ct], 0, 0, 0);
            acc[ct] = __builtin_amdgcn_mfma_f32_16x16x32_f16(Alo, Bf[ct], acc[ct], 0, 0, 0);
        }
    }

    const float* bias = (wsel == 0) ? bq : (wsel == 1) ? bk : bv;

    if (wsel < 2) {
        h1* f = (wsel == 0) ? fq : fk;
#pragma unroll
        for (int ct = 0; ct < 8; ++ct) {
            const int c = ct * 16 + l15;
            const float bb = bias[hg * 128 + c];
            const int hh4 = c >> 5, dd = c & 31;
#pragma unroll
            for (int r = 0; r < 4; ++r) {
                const float val = acc[ct][r] + bb;
                const float sv = __sinf(val), cv = __cosf(val);
                h1* fp = &fbuf[w * 16 + quad * 4 + r][hh4 * 64 + dd];
                fp[0]  = (h1)cv;
                fp[32] = (h1)sv;
            }
        }
        __syncthreads();
        const int row = tid >> 2, q4 = tid & 3;
#pragma unroll
        for (int g = 0; g < 8; ++g) {
            const int chunk = q4 + g * 4;
            const int hh4 = chunk >> 3, within = chunk & 7;
            const h8 val = *(const h8*)&fbuf[row][hh4 * 64 + within * 8];
            const int head = hg * 4 + hh4;
            *(h8*)&f[((size_t)(b * Hn + head) * Nn + n0 + row) * 64 + within * 8] = val;
        }
    } else {
        h1 (*vst)[132] = (h1(*)[132])fbuf;
#pragma unroll
        for (int ct = 0; ct < 8; ++ct) {
            const int c = ct * 16 + l15;
            const float bb = bias[hg * 128 + c];
#pragma unroll
            for (int r = 0; r < 4; ++r)
                vst[w * 16 + quad * 4 + r][c] = (h1)(acc[ct][r] + bb);
        }
        __syncthreads();
        const int c2 = tid & 127, half = tid >> 7;
        const int head = hg * 4 + (c2 >> 5), dd = c2 & 31;
        h1* vp = vT + ((size_t)((b * Hn + head) * HDn + dd)) * Nn + n0;
#pragma unroll
        for (int g = 0; g < 4; ++g) {
            const int gg = half * 4 + g;
            h8 pk;
#pragma unroll
            for (int j = 0; j < 8; ++j) pk[j] = vst[gg * 8 + j][c2];
            *(h8*)(vp + gg * 8) = pk;
        }
    }
}

// ---------------------------------------------------------------------------
// Kernel 2: fused attention. Block = 512 thr = 8 waves = ALL 8 heads of one
// (b, 32 q-rows, m-half) -> topo tile shared block-wide (67 MB HBM minimum).
//
// r8 (NT=16 + waves_per_eu 8) POST-MORTEM: occupancy 41->73% but 1.8x SLOWER.
// VGPR forced to 32 -> K/V fragment loads serialized (load-wait-use), L2
// latency exposed several times per iteration. Occupancy was never the
// bottleneck: grid 512 = 2 blocks/CU is the cap; VGPR budget at (512,4) is
// 128 and baseline used only 52.
//
// r9 CHANGE: NT back to 32; spend the spare registers on a K/V REGISTER
// DOUBLE-BUFFER. Iteration it issues iter it+1's kfr/bV global loads at the
// top, BEFORE the raw barrier (lgkmcnt-only, so the loads stay in flight
// across it); the S/PV MFMAs consume fragments loaded one iteration ago.
// The L2 latency is thus hidden under a full iteration of compute instead
// of being on the critical path. Loop unrolled x2 with named A/B buffers
// (static register indexing). Topo keeps its existing 1-ahead register +
// LDS double-buffer pipeline. Fixed-shift softmax: no reductions in loop.
// ---------------------------------------------------------------------------
__global__ __launch_bounds__(512, 4) void attn_kernel(
    const h1* __restrict__ fq, const h1* __restrict__ fk, const h1* __restrict__ vT,
    const float* __restrict__ topo, float* __restrict__ pacc, float* __restrict__ pl)
{
    __shared__ __align__(16) h1 Pw[8][32][40];   // 20 KB per-wave P buffers
    __shared__ float tbuf[2][32][33];            // 8.4 KB topo double buffer

    const int b = blockIdx.y;
    const int mh = blockIdx.z;
    const int n0 = blockIdx.x * 32;
    const int tid = threadIdx.x;
    const int w = tid >> 6;        // wave id = head
    const int h = w;
    const int lane = tid & 63;
    const int quad = lane >> 4;
    const int l15 = lane & 15;

    const h1* qfh = fq + (size_t)(b * Hn + h) * Nn * 64;
    const h1* kfh = fk + (size_t)(b * Hn + h) * Nn * 64;
    const h1* vTh = vT + (size_t)(b * Hn + h) * HDn * Nn;

    // topo cooperative-load mapping: thread -> (row, 2 cols)
    const int trow = tid >> 4, tcol = (tid & 15) * 2;
    const float* tpg = topo + (size_t)b * Nn * Nn + (size_t)(n0 + trow) * Nn + tcol;

    h8 qfr[2][2];
#pragma unroll
    for (int qs = 0; qs < 2; ++qs)
#pragma unroll
        for (int ks = 0; ks < 2; ++ks)
            qfr[qs][ks] = *(const h8*)(qfh + (size_t)(n0 + qs * 16 + l15) * 64 + ks * 32 + quad * 8);

    fx4 acc[2][2];
    float lsum[2][4];
#pragma unroll
    for (int qs = 0; qs < 2; ++qs) {
#pragma unroll
        for (int ds = 0; ds < 2; ++ds) acc[qs][ds] = (fx4){0.f, 0.f, 0.f, 0.f};
#pragma unroll
        for (int r = 0; r < 4; ++r) lsum[qs][r] = 0.f;
    }

    const int mbase = mh * MHALF;
    const int NITER = MHALF / 32;
    const fx4 z4 = {0.f, 0.f, 0.f, 0.f};

    // K/V fragment loader (all-register destination, statically indexed)
    auto loadKV = [&](int m0, h8 (&kf)[2][2], h8 (&bv)[2]) {
#pragma unroll
        for (int ms = 0; ms < 2; ++ms)
#pragma unroll
            for (int ks = 0; ks < 2; ++ks)
                kf[ms][ks] = *(const h8*)(kfh + (size_t)(m0 + ms * 16 + l15) * 64 + ks * 32 + quad * 8);
#pragma unroll
        for (int ds = 0; ds < 2; ++ds)
            bv[ds] = *(const h8*)(vTh + (size_t)(ds * 16 + l15) * Nn + m0 + quad * 8);
    };

    h8 kA[2][2], kB[2][2], vA[2], vB[2];
    loadKV(mbase, kA, vA);                       // prefetch K/V tile 0
    float2 rt = *(const float2*)(tpg + mbase);   // prefetch topo tile 0

    auto iter = [&](int it, h8 (&kc)[2][2], h8 (&vc)[2],
                            h8 (&kn)[2][2], h8 (&vn)[2]) {
        const int m0 = mbase + it * 32;
        const int cur = it & 1;
        const bool more = (it < NITER - 1);

        // issue NEXT tile's K/V loads first -- they complete under this
        // iteration's compute; counted vmcnt keeps them off the critical path
        if (more) loadKV(m0 + 32, kn, vn);

        // commit prefetched topo tile to LDS, issue next tile's topo load
        tbuf[cur][trow][tcol]     = rt.x;
        tbuf[cur][trow][tcol + 1] = rt.y;
        if (more) rt = *(const float2*)(tpg + m0 + 32);
        // raw barrier: waits own LDS writes only; global prefetch stays in flight
        __asm__ volatile("s_waitcnt lgkmcnt(0)\n\ts_barrier" ::: "memory");

        // S = Qf @ Kf^T from registers loaded one iteration ago
        fx4 S[2][2];
#pragma unroll
        for (int qs = 0; qs < 2; ++qs)
#pragma unroll
            for (int ms = 0; ms < 2; ++ms) {
                fx4 tmp = __builtin_amdgcn_mfma_f32_16x16x32_f16(qfr[qs][0], kc[ms][0], z4, 0, 0, 0);
                S[qs][ms] = __builtin_amdgcn_mfma_f32_16x16x32_f16(qfr[qs][1], kc[ms][1], tmp, 0, 0, 0);
            }

        // p = e^{S*topo*QSCALE - 4}; topo from LDS (pad 33 -> 2-way-free banks)
#pragma unroll
        for (int qs = 0; qs < 2; ++qs)
#pragma unroll
            for (int ms = 0; ms < 2; ++ms)
#pragma unroll
                for (int r = 0; r < 4; ++r) {
                    const float tv = tbuf[cur][qs * 16 + quad * 4 + r][ms * 16 + l15];
                    const float p = __expf(fmaf(S[qs][ms][r] * tv, QSCALE, -SOFTMAX_SHIFT));
                    lsum[qs][r] += p;
                    Pw[w][qs * 16 + quad * 4 + r][ms * 16 + l15] = (h1)p;
                }
        __asm__ volatile("s_waitcnt lgkmcnt(0)" ::: "memory");

        // PV from registers loaded one iteration ago
        h8 aP[2];
#pragma unroll
        for (int qs = 0; qs < 2; ++qs)
            aP[qs] = *(const h8*)&Pw[w][qs * 16 + l15][quad * 8];
#pragma unroll
        for (int qs = 0; qs < 2; ++qs)
#pragma unroll
            for (int ds = 0; ds < 2; ++ds)
                acc[qs][ds] = __builtin_amdgcn_mfma_f32_16x16x32_f16(aP[qs], vc[ds], acc[qs][ds], 0, 0, 0);
    };

    for (int it = 0; it < NITER; it += 2) {
        iter(it,     kA, vA, kB, vB);
        iter(it + 1, kB, vB, kA, vA);
    }

    // epilogue: reduce l across the 16 col-lanes, write partials
#pragma unroll
    for (int qs = 0; qs < 2; ++qs)
#pragma unroll
        for (int r = 0; r < 4; ++r)
#pragma unroll
            for (int off = 1; off <= 8; off <<= 1)
                lsum[qs][r] += __shfl_xor(lsum[qs][r], off);

    float* paccm = pacc + (size_t)mh * Bn * Nn * Dn;
    float* plm   = pl   + (size_t)mh * Bn * Nn * Hn;
#pragma unroll
    for (int qs = 0; qs < 2; ++qs)
#pragma unroll
        for (int r = 0; r < 4; ++r) {
            const size_t grow = (size_t)b * Nn + n0 + qs * 16 + quad * 4 + r;
            paccm[grow * Dn + h * HDn + l15]      = acc[qs][0][r];
            paccm[grow * Dn + h * HDn + 16 + l15] = acc[qs][1][r];
            if (l15 == 0) plm[grow * Hn + h] = lsum[qs][r];
        }
}

// ---------------------------------------------------------------------------
// Kernel 3: merge 2 partials + output projection. 8 rows/block, thread=col.
// ---------------------------------------------------------------------------
__global__ __launch_bounds__(256) void oproj_kernel(
    const float* __restrict__ pacc, const float* __restrict__ pl,
    const float* __restrict__ Wo, const float* __restrict__ bo,
    float* __restrict__ out)
{
    __shared__ float ysT[256][12];
    const int t = threadIdx.x;
    const int r0 = blockIdx.x * 8;
    const int h = t >> 5;
    const size_t PACC = (size_t)Bn * Nn * Dn;
    const size_t PL = (size_t)Bn * Nn * Hn;
#pragma unroll
    for (int i = 0; i < 8; ++i) {
        const size_t row = (size_t)(r0 + i);
        float l = 0.f, yv = 0.f;
#pragma unroll
        for (int m = 0; m < 2; ++m) {
            l  += pl[m * PL + row * Hn + h];
            yv += pacc[m * PACC + row * Dn + t];
        }
        ysT[t][i] = yv * __builtin_amdgcn_rcpf(l);
    }
    __syncthreads();

    float acc8[8];
#pragma unroll
    for (int i = 0; i < 8; ++i) acc8[i] = 0.f;
#pragma unroll 4
    for (int d = 0; d < 256; ++d) {
        const float wv = Wo[d * 256 + t];
        float yy[8];
        *(float4*)&yy[0] = *(const float4*)&ysT[d][0];
        *(float4*)&yy[4] = *(const float4*)&ysT[d][4];
#pragma unroll
        for (int i = 0; i < 8; ++i) acc8[i] = fmaf(yy[i], wv, acc8[i]);
    }
    const float bb = bo[t];
#pragma unroll
    for (int i = 0; i < 8; ++i)
        out[(size_t)(r0 + i) * 256 + t] = acc8[i] + bb;
}

// ---------------------------------------------------------------------------
extern "C" void kernel_launch(void* const* d_in, const int* in_sizes, int n_in,
                              void* d_out, int out_size, void* d_ws, size_t ws_size,
                              hipStream_t stream)
{
    const float* x    = (const float*)d_in[0];
    const float* topo = (const float*)d_in[1];
    const float* Wq   = (const float*)d_in[2];
    const float* bq   = (const float*)d_in[3];
    const float* Wk   = (const float*)d_in[4];
    const float* bk   = (const float*)d_in[5];
    const float* Wv   = (const float*)d_in[6];
    const float* bv   = (const float*)d_in[7];
    const float* Wo   = (const float*)d_in[8];
    const float* bo   = (const float*)d_in[9];
    float* out = (float*)d_out;

    char* ws = (char*)d_ws;
    const size_t MB = 1024 * 1024;
    h1* WT = (h1*)ws;
    h1* fq = (h1*)(ws + 1 * MB);
    h1* fk = (h1*)(ws + 9 * MB);
    h1* vT = (h1*)(ws + 17 * MB);
    float* pacc = (float*)(ws + 21 * MB);
    float* pl   = (float*)(ws + 37 * MB);

    cvtW_kernel<<<dim3(4, 4, 3), 256, 0, stream>>>(Wq, Wk, Wv, WT);
    proj_kernel<<<dim3(128, 6), 256, 0, stream>>>(x, WT, bq, bk, bv, fq, fk, vT);
    attn_kernel<<<dim3(Nn / 32, Bn, 2), 512, 0, stream>>>(fq, fk, vT, topo, pacc, pl);
    oproj_kernel<<<(Bn * Nn) / 8, 256, 0, stream>>>(pacc, pl, Wo, bo, out);
}